// Round 1
// baseline (3466.121 us; speedup 1.0000x reference)
//
#include <hip/hip_runtime.h>

// ---------------- kernels ----------------

__global__ void k_zero4(float4* p, int n4) {
    int i = blockIdx.x * 256 + threadIdx.x;
    if (i < n4) p[i] = make_float4(0.f, 0.f, 0.f, 0.f);
}

__global__ void k_deg(const int* __restrict__ dst, int* __restrict__ deg, int E) {
    int i = blockIdx.x * 256 + threadIdx.x;
    if (i < E) atomicAdd(&deg[dst[i]], 1);
}

__global__ void k_dinv(const int* __restrict__ deg, float* __restrict__ dinv, int n) {
    int i = blockIdx.x * 256 + threadIdx.x;
    if (i < n) {
        int d = deg[i];
        dinv[i] = d > 0 ? rsqrtf((float)d) : 0.f;
    }
}

__global__ void k_norm(const int* __restrict__ src, const int* __restrict__ dst,
                       const float* __restrict__ dinv, float* __restrict__ nrm, int E) {
    int i = blockIdx.x * 256 + threadIdx.x;
    if (i < E) nrm[i] = dinv[src[i]] * dinv[dst[i]];
}

// C[N x 128] = A[N x 128] @ W[128 x 128]; W staged in LDS (64 KB).
// 256 threads: each thread does 4 cols x 8 row-passes (64 rows/block).
__global__ __launch_bounds__(256) void k_gemm128(const float* __restrict__ A,
                                                 const float* __restrict__ W,
                                                 float* __restrict__ C, int nrows) {
    __shared__ float ws[128 * 128];
    for (int i = threadIdx.x; i < 128 * 128 / 4; i += 256)
        ((float4*)ws)[i] = ((const float4*)W)[i];
    __syncthreads();

    const int col4 = (threadIdx.x & 31) * 4;
    const int rloc = threadIdx.x >> 5;   // 0..7
    const int rowbase = blockIdx.x * 64;
    for (int rp = 0; rp < 8; ++rp) {
        int row = rowbase + rp * 8 + rloc;
        if (row < nrows) {
            const float* a = A + (size_t)row * 128;
            float4 acc = make_float4(0.f, 0.f, 0.f, 0.f);
            for (int kk = 0; kk < 32; ++kk) {
                float4 a4 = ((const float4*)a)[kk];
#pragma unroll
                for (int j = 0; j < 4; ++j) {
                    float av = j == 0 ? a4.x : j == 1 ? a4.y : j == 2 ? a4.z : a4.w;
                    float4 w4 = *(const float4*)&ws[(kk * 4 + j) * 128 + col4];
                    acc.x += av * w4.x; acc.y += av * w4.y;
                    acc.z += av * w4.z; acc.w += av * w4.w;
                }
            }
            *(float4*)&C[(size_t)row * 128 + col4] = acc;
        }
    }
}

// out[dst] += norm * H[src], F=128, 32 threads/edge, float4 each
__global__ void k_scatter128(const float* __restrict__ H, const int* __restrict__ src,
                             const int* __restrict__ dst, const float* __restrict__ nrm,
                             float* __restrict__ out, long total) {
    long i = (long)blockIdx.x * 256 + threadIdx.x;
    if (i >= total) return;
    int e = (int)(i >> 5);
    int f4 = ((int)i & 31) * 4;
    int s = src[e], d = dst[e];
    float w = nrm[e];
    float4 v = *(const float4*)&H[(size_t)s * 128 + f4];
    float* o = &out[(size_t)d * 128 + f4];
    atomicAdd(o + 0, w * v.x);
    atomicAdd(o + 1, w * v.y);
    atomicAdd(o + 2, w * v.z);
    atomicAdd(o + 3, w * v.w);
}

__global__ void k_bnstats(const float* __restrict__ H, float* __restrict__ sums,
                          float* __restrict__ sumsq, int nrows) {
    int col = threadIdx.x & 127;
    int half = threadIdx.x >> 7;
    float s = 0.f, q = 0.f;
    for (int r = blockIdx.x * 2 + half; r < nrows; r += gridDim.x * 2) {
        float v = H[(size_t)r * 128 + col];
        s += v; q += v * v;
    }
    __shared__ float ls[256], lq[256];
    ls[threadIdx.x] = s; lq[threadIdx.x] = q;
    __syncthreads();
    if (threadIdx.x < 128) {
        s = ls[threadIdx.x] + ls[threadIdx.x + 128];
        q = lq[threadIdx.x] + lq[threadIdx.x + 128];
        atomicAdd(&sums[threadIdx.x], s);
        atomicAdd(&sumsq[threadIdx.x], q);
    }
}

__global__ void k_bnfinal(const float* __restrict__ sums, const float* __restrict__ sumsq,
                          const float* __restrict__ g, const float* __restrict__ beta,
                          float* __restrict__ scale, float* __restrict__ shift, int nrows) {
    int c = threadIdx.x;
    float inv_n = 1.f / (float)nrows;
    float mu = sums[c] * inv_n;
    float var = sumsq[c] * inv_n - mu * mu;
    float rs = rsqrtf(var + 1e-5f);
    float sc = rs * g[c];
    scale[c] = sc;
    shift[c] = beta[c] - mu * sc;
}

__global__ void k_bnrelu(const float4* __restrict__ in, const float* __restrict__ scale,
                         const float* __restrict__ shift, float4* __restrict__ out, int n4) {
    int i = blockIdx.x * 256 + threadIdx.x;
    if (i >= n4) return;
    int c4 = (i & 31) * 4;
    float4 v = in[i];
    float4 sc = *(const float4*)&scale[c4];
    float4 sh = *(const float4*)&shift[c4];
    float4 r;
    r.x = fmaxf(v.x * sc.x + sh.x, 0.f);
    r.y = fmaxf(v.y * sc.y + sh.y, 0.f);
    r.z = fmaxf(v.z * sc.z + sh.z, 0.f);
    r.w = fmaxf(v.w * sc.w + sh.w, 0.f);
    out[i] = r;
}

// C[N x 40] = A[N x 128] @ W[128 x 40]
__global__ __launch_bounds__(256) void k_gemm40(const float* __restrict__ A,
                                                const float* __restrict__ W,
                                                float* __restrict__ C, int nrows) {
    __shared__ float ws[128 * 40];
    for (int i = threadIdx.x; i < 128 * 40 / 4; i += 256)
        ((float4*)ws)[i] = ((const float4*)W)[i];
    __syncthreads();
    long idx = (long)blockIdx.x * 256 + threadIdx.x;
    long total = (long)nrows * 40;
    if (idx >= total) return;
    int row = (int)(idx / 40);
    int col = (int)(idx % 40);
    const float* a = A + (size_t)row * 128;
    float acc = 0.f;
    for (int kk = 0; kk < 32; ++kk) {
        float4 a4 = ((const float4*)a)[kk];
        acc += a4.x * ws[(kk * 4 + 0) * 40 + col];
        acc += a4.y * ws[(kk * 4 + 1) * 40 + col];
        acc += a4.z * ws[(kk * 4 + 2) * 40 + col];
        acc += a4.w * ws[(kk * 4 + 3) * 40 + col];
    }
    C[idx] = acc;
}

__global__ void k_initout(const float* __restrict__ b3, float* __restrict__ out, long total) {
    long i = (long)blockIdx.x * 256 + threadIdx.x;
    if (i < total) out[i] = b3[i % 40];
}

// out[dst] += norm * H[src], F=40, 10 threads/edge, float4 each
__global__ void k_scatter40(const float* __restrict__ H, const int* __restrict__ src,
                            const int* __restrict__ dst, const float* __restrict__ nrm,
                            float* __restrict__ out, long total) {
    long i = (long)blockIdx.x * 256 + threadIdx.x;
    if (i >= total) return;
    int e = (int)(i / 10);
    int f4 = (int)(i % 10) * 4;
    int s = src[e], d = dst[e];
    float w = nrm[e];
    float4 v = *(const float4*)&H[(size_t)s * 40 + f4];
    float* o = &out[(size_t)d * 40 + f4];
    atomicAdd(o + 0, w * v.x);
    atomicAdd(o + 1, w * v.y);
    atomicAdd(o + 2, w * v.z);
    atomicAdd(o + 3, w * v.w);
}

// ---------------- launch ----------------

extern "C" void kernel_launch(void* const* d_in, const int* in_sizes, int n_in,
                              void* d_out, int out_size, void* d_ws, size_t ws_size,
                              hipStream_t stream) {
    const float* x  = (const float*)d_in[0];
    const int*   ei = (const int*)d_in[1];
    const float* W1 = (const float*)d_in[2];
    const float* g1 = (const float*)d_in[4];
    const float* be1= (const float*)d_in[5];
    const float* W2 = (const float*)d_in[6];
    const float* g2 = (const float*)d_in[8];
    const float* be2= (const float*)d_in[9];
    const float* W3 = (const float*)d_in[10];
    const float* b3 = (const float*)d_in[11];

    const int N = in_sizes[0] / 128;
    const int E = in_sizes[1] / 2;
    const int* srcv = ei;
    const int* dstv = ei + E;

    float* wsf   = (float*)d_ws;
    float* bufA  = wsf;
    float* bufB  = bufA + (size_t)N * 128;
    float* t3    = bufB + (size_t)N * 128;
    float* nrm   = t3 + (size_t)N * 40;
    float* dinv  = nrm + E;
    int*   deg   = (int*)(dinv + N);
    float* sums  = (float*)(deg + N);   // 128
    float* sumsq = sums + 128;          // 128
    float* scale = sumsq + 128;         // 128
    float* shift = scale + 128;         // 128
    float* out   = (float*)d_out;

    const int n4_128 = N * 128 / 4;
    const long tot128 = (long)E * 32;
    const long tot40  = (long)E * 10;
    const long nout   = (long)N * 40;

    // degree + norm
    int degn4 = N * 4 / 16;  // N ints in float4 units
    k_zero4<<<(degn4 + 255) / 256, 256, 0, stream>>>((float4*)deg, degn4);
    k_deg<<<(E + 255) / 256, 256, 0, stream>>>(dstv, deg, E);
    k_dinv<<<(N + 255) / 256, 256, 0, stream>>>(deg, dinv, N);
    k_norm<<<(E + 255) / 256, 256, 0, stream>>>(srcv, dstv, dinv, nrm, E);

    // ---- layer 1 ----
    k_gemm128<<<(N + 63) / 64, 256, 0, stream>>>(x, W1, bufA, N);
    k_zero4<<<(n4_128 + 255) / 256, 256, 0, stream>>>((float4*)bufB, n4_128);
    k_scatter128<<<(int)((tot128 + 255) / 256), 256, 0, stream>>>(bufA, srcv, dstv, nrm, bufB, tot128);
    k_zero4<<<1, 256, 0, stream>>>((float4*)sums, 64);
    k_bnstats<<<256, 256, 0, stream>>>(bufB, sums, sumsq, N);
    k_bnfinal<<<1, 128, 0, stream>>>(sums, sumsq, g1, be1, scale, shift, N);
    k_bnrelu<<<(n4_128 + 255) / 256, 256, 0, stream>>>((const float4*)bufB, scale, shift, (float4*)bufA, n4_128);

    // ---- layer 2 ----
    k_gemm128<<<(N + 63) / 64, 256, 0, stream>>>(bufA, W2, bufB, N);
    k_zero4<<<(n4_128 + 255) / 256, 256, 0, stream>>>((float4*)bufA, n4_128);
    k_scatter128<<<(int)((tot128 + 255) / 256), 256, 0, stream>>>(bufB, srcv, dstv, nrm, bufA, tot128);
    k_zero4<<<1, 256, 0, stream>>>((float4*)sums, 64);
    k_bnstats<<<256, 256, 0, stream>>>(bufA, sums, sumsq, N);
    k_bnfinal<<<1, 128, 0, stream>>>(sums, sumsq, g2, be2, scale, shift, N);
    k_bnrelu<<<(n4_128 + 255) / 256, 256, 0, stream>>>((const float4*)bufA, scale, shift, (float4*)bufB, n4_128);

    // ---- layer 3 ----
    k_gemm40<<<(int)((nout + 255) / 256), 256, 0, stream>>>(bufB, W3, t3, N);
    k_initout<<<(int)((nout + 255) / 256), 256, 0, stream>>>(b3, out, nout);
    k_scatter40<<<(int)((tot40 + 255) / 256), 256, 0, stream>>>(t3, srcv, dstv, nrm, out, tot40);
}

// Round 2
// 495.161 us; speedup vs baseline: 7.0000x; 7.0000x over previous
//
#include <hip/hip_runtime.h>

// ---------------- utility ----------------

__global__ void k_zero4(float4* p, int n4) {
    int i = blockIdx.x * 256 + threadIdx.x;
    if (i < n4) p[i] = make_float4(0.f, 0.f, 0.f, 0.f);
}

// ---------------- CSR build (counting sort by dst) ----------------

__global__ void k_deg(const int* __restrict__ dst, int* __restrict__ deg, int E) {
    int i = blockIdx.x * 256 + threadIdx.x;
    if (i < E) atomicAdd(&deg[dst[i]], 1);
}

__global__ void k_dinv(const int* __restrict__ deg, float* __restrict__ dinv, int n) {
    int i = blockIdx.x * 256 + threadIdx.x;
    if (i < n) {
        int d = deg[i];
        dinv[i] = d > 0 ? rsqrtf((float)d) : 0.f;
    }
}

__global__ void k_blocksum(const int* __restrict__ deg, int* __restrict__ bsum, int n) {
    __shared__ int ls[256];
    int i = blockIdx.x * 256 + threadIdx.x;
    ls[threadIdx.x] = i < n ? deg[i] : 0;
    __syncthreads();
    for (int off = 128; off > 0; off >>= 1) {
        if (threadIdx.x < off) ls[threadIdx.x] += ls[threadIdx.x + off];
        __syncthreads();
    }
    if (threadIdx.x == 0) bsum[blockIdx.x] = ls[0];
}

__global__ void k_scanbsum(int* bsum, int nb) {
    if (threadIdx.x == 0 && blockIdx.x == 0) {
        int acc = 0;
        for (int i = 0; i < nb; ++i) { int v = bsum[i]; bsum[i] = acc; acc += v; }
    }
}

__global__ void k_scanchunk(const int* __restrict__ deg, const int* __restrict__ bsum,
                            int* __restrict__ row_ptr, int* __restrict__ cursor,
                            int n, int E) {
    __shared__ int ls[256];
    int i = blockIdx.x * 256 + threadIdx.x;
    int v = i < n ? deg[i] : 0;
    ls[threadIdx.x] = v;
    __syncthreads();
    for (int off = 1; off < 256; off <<= 1) {
        int t = threadIdx.x >= off ? ls[threadIdx.x - off] : 0;
        __syncthreads();
        ls[threadIdx.x] += t;
        __syncthreads();
    }
    if (i < n) {
        int ex = ls[threadIdx.x] - v + bsum[blockIdx.x];  // exclusive
        row_ptr[i] = ex;
        cursor[i] = ex;
    }
    if (i == n - 1) row_ptr[n] = E;
}

__global__ void k_place(const int* __restrict__ src, const int* __restrict__ dst,
                        int* __restrict__ cursor, int* __restrict__ sidx, int E) {
    int i = blockIdx.x * 256 + threadIdx.x;
    if (i < E) {
        int pos = atomicAdd(&cursor[dst[i]], 1);
        sidx[pos] = src[i];
    }
}

// ---------------- GEMM (epilogue scaled by dinv[row]) ----------------

// C[row] = dinv[row] * (A[row] @ W), F=128. W staged in LDS (64 KB).
__global__ __launch_bounds__(256) void k_gemm128(const float* __restrict__ A,
                                                 const float* __restrict__ W,
                                                 const float* __restrict__ dinv,
                                                 float* __restrict__ C, int nrows) {
    __shared__ float ws[128 * 128];
    for (int i = threadIdx.x; i < 128 * 128 / 4; i += 256)
        ((float4*)ws)[i] = ((const float4*)W)[i];
    __syncthreads();

    const int col4 = (threadIdx.x & 31) * 4;
    const int rloc = threadIdx.x >> 5;   // 0..7
    const int rowbase = blockIdx.x * 64;
    for (int rp = 0; rp < 8; ++rp) {
        int row = rowbase + rp * 8 + rloc;
        if (row < nrows) {
            const float* a = A + (size_t)row * 128;
            float4 acc = make_float4(0.f, 0.f, 0.f, 0.f);
            for (int kk = 0; kk < 32; ++kk) {
                float4 a4 = ((const float4*)a)[kk];
#pragma unroll
                for (int j = 0; j < 4; ++j) {
                    float av = j == 0 ? a4.x : j == 1 ? a4.y : j == 2 ? a4.z : a4.w;
                    float4 w4 = *(const float4*)&ws[(kk * 4 + j) * 128 + col4];
                    acc.x += av * w4.x; acc.y += av * w4.y;
                    acc.z += av * w4.z; acc.w += av * w4.w;
                }
            }
            float sc = dinv[row];
            acc.x *= sc; acc.y *= sc; acc.z *= sc; acc.w *= sc;
            *(float4*)&C[(size_t)row * 128 + col4] = acc;
        }
    }
}

// C[row] = dinv[row] * (A[row] @ W), F_out=40
__global__ __launch_bounds__(256) void k_gemm40(const float* __restrict__ A,
                                                const float* __restrict__ W,
                                                const float* __restrict__ dinv,
                                                float* __restrict__ C, int nrows) {
    __shared__ float ws[128 * 40];
    for (int i = threadIdx.x; i < 128 * 40 / 4; i += 256)
        ((float4*)ws)[i] = ((const float4*)W)[i];
    __syncthreads();
    long idx = (long)blockIdx.x * 256 + threadIdx.x;
    long total = (long)nrows * 40;
    if (idx >= total) return;
    int row = (int)(idx / 40);
    int col = (int)(idx % 40);
    const float* a = A + (size_t)row * 128;
    float acc = 0.f;
    for (int kk = 0; kk < 32; ++kk) {
        float4 a4 = ((const float4*)a)[kk];
        acc += a4.x * ws[(kk * 4 + 0) * 40 + col];
        acc += a4.y * ws[(kk * 4 + 1) * 40 + col];
        acc += a4.z * ws[(kk * 4 + 2) * 40 + col];
        acc += a4.w * ws[(kk * 4 + 3) * 40 + col];
    }
    C[idx] = acc * dinv[row];
}

// ---------------- CSR gather-aggregate ----------------

// out[d] = dinv[d] * sum_{j in [rp[d],rp[d+1])} H[sidx[j]], F=128.
// 32 lanes per node, float4 per lane; 8 nodes per 256-thread block.
__global__ __launch_bounds__(256) void k_agg128(const float4* __restrict__ H,
                                                const int* __restrict__ rp,
                                                const int* __restrict__ sidx,
                                                const float* __restrict__ dinv,
                                                float4* __restrict__ out, int n) {
    int d = blockIdx.x * 8 + (threadIdx.x >> 5);
    if (d >= n) return;
    int lane = threadIdx.x & 31;
    int beg = rp[d], end = rp[d + 1];
    float4 acc = make_float4(0.f, 0.f, 0.f, 0.f);
    for (int j = beg; j < end; ++j) {
        int s = sidx[j];
        float4 v = H[(size_t)s * 32 + lane];
        acc.x += v.x; acc.y += v.y; acc.z += v.z; acc.w += v.w;
    }
    float sc = dinv[d];
    acc.x *= sc; acc.y *= sc; acc.z *= sc; acc.w *= sc;
    out[(size_t)d * 32 + lane] = acc;
}

// out[d] = dinv[d] * sum H3[sidx[j]] + b3, F=40. One thread per (node, col4).
__global__ void k_agg40(const float4* __restrict__ H,
                        const int* __restrict__ rp,
                        const int* __restrict__ sidx,
                        const float* __restrict__ dinv,
                        const float* __restrict__ b3,
                        float4* __restrict__ out, int n) {
    int i = blockIdx.x * 256 + threadIdx.x;
    if (i >= n * 10) return;
    int d = i / 10, q = i % 10;
    int beg = rp[d], end = rp[d + 1];
    float4 acc = make_float4(0.f, 0.f, 0.f, 0.f);
    for (int j = beg; j < end; ++j) {
        int s = sidx[j];
        float4 v = H[(size_t)s * 10 + q];
        acc.x += v.x; acc.y += v.y; acc.z += v.z; acc.w += v.w;
    }
    float sc = dinv[d];
    float4 b = *(const float4*)&b3[q * 4];
    acc.x = acc.x * sc + b.x; acc.y = acc.y * sc + b.y;
    acc.z = acc.z * sc + b.z; acc.w = acc.w * sc + b.w;
    out[i] = acc;
}

// ---------------- BatchNorm + ReLU ----------------

__global__ void k_bnstats(const float* __restrict__ H, float* __restrict__ sums,
                          float* __restrict__ sumsq, int nrows) {
    int col = threadIdx.x & 127;
    int half = threadIdx.x >> 7;
    float s = 0.f, q = 0.f;
    for (int r = blockIdx.x * 2 + half; r < nrows; r += gridDim.x * 2) {
        float v = H[(size_t)r * 128 + col];
        s += v; q += v * v;
    }
    __shared__ float ls[256], lq[256];
    ls[threadIdx.x] = s; lq[threadIdx.x] = q;
    __syncthreads();
    if (threadIdx.x < 128) {
        s = ls[threadIdx.x] + ls[threadIdx.x + 128];
        q = lq[threadIdx.x] + lq[threadIdx.x + 128];
        atomicAdd(&sums[threadIdx.x], s);
        atomicAdd(&sumsq[threadIdx.x], q);
    }
}

__global__ void k_bnfinal(const float* __restrict__ sums, const float* __restrict__ sumsq,
                          const float* __restrict__ g, const float* __restrict__ beta,
                          float* __restrict__ scale, float* __restrict__ shift, int nrows) {
    int c = threadIdx.x;
    float inv_n = 1.f / (float)nrows;
    float mu = sums[c] * inv_n;
    float var = sumsq[c] * inv_n - mu * mu;
    float rs = rsqrtf(var + 1e-5f);
    float sc = rs * g[c];
    scale[c] = sc;
    shift[c] = beta[c] - mu * sc;
}

__global__ void k_bnrelu(const float4* __restrict__ in, const float* __restrict__ scale,
                         const float* __restrict__ shift, float4* __restrict__ out, int n4) {
    int i = blockIdx.x * 256 + threadIdx.x;
    if (i >= n4) return;
    int c4 = (i & 31) * 4;
    float4 v = in[i];
    float4 sc = *(const float4*)&scale[c4];
    float4 sh = *(const float4*)&shift[c4];
    float4 r;
    r.x = fmaxf(v.x * sc.x + sh.x, 0.f);
    r.y = fmaxf(v.y * sc.y + sh.y, 0.f);
    r.z = fmaxf(v.z * sc.z + sh.z, 0.f);
    r.w = fmaxf(v.w * sc.w + sh.w, 0.f);
    out[i] = r;
}

// ---------------- launch ----------------

extern "C" void kernel_launch(void* const* d_in, const int* in_sizes, int n_in,
                              void* d_out, int out_size, void* d_ws, size_t ws_size,
                              hipStream_t stream) {
    const float* x  = (const float*)d_in[0];
    const int*   ei = (const int*)d_in[1];
    const float* W1 = (const float*)d_in[2];
    const float* g1 = (const float*)d_in[4];
    const float* be1= (const float*)d_in[5];
    const float* W2 = (const float*)d_in[6];
    const float* g2 = (const float*)d_in[8];
    const float* be2= (const float*)d_in[9];
    const float* W3 = (const float*)d_in[10];
    const float* b3 = (const float*)d_in[11];

    const int N = in_sizes[0] / 128;
    const int E = in_sizes[1] / 2;
    const int* srcv = ei;
    const int* dstv = ei + E;
    const int NB = (N + 255) / 256;

    float* wsf     = (float*)d_ws;
    float* bufA    = wsf;
    float* bufB    = bufA + (size_t)N * 128;
    float* t3      = bufB + (size_t)N * 128;
    float* dinv    = t3 + (size_t)N * 40;
    int*   deg     = (int*)(dinv + N);
    int*   row_ptr = deg + N;          // N+1
    int*   cursor  = row_ptr + N + 1;  // N
    int*   sidx    = cursor + N;       // E
    int*   bsum    = sidx + E;         // NB
    float* sums    = (float*)(bsum + NB + 1);
    float* sumsq   = sums + 128;
    float* scale   = sumsq + 128;
    float* shift   = scale + 128;
    float* out     = (float*)d_out;

    const int n4_128 = N * 128 / 4;

    // ---- CSR build + dinv ----
    k_zero4<<<(N / 4 + 255) / 256, 256, 0, stream>>>((float4*)deg, N / 4);
    k_deg<<<(E + 255) / 256, 256, 0, stream>>>(dstv, deg, E);
    k_dinv<<<(N + 255) / 256, 256, 0, stream>>>(deg, dinv, N);
    k_blocksum<<<NB, 256, 0, stream>>>(deg, bsum, N);
    k_scanbsum<<<1, 64, 0, stream>>>(bsum, NB);
    k_scanchunk<<<NB, 256, 0, stream>>>(deg, bsum, row_ptr, cursor, N, E);
    k_place<<<(E + 255) / 256, 256, 0, stream>>>(srcv, dstv, cursor, sidx, E);

    // ---- layer 1 ----
    k_gemm128<<<(N + 63) / 64, 256, 0, stream>>>(x, W1, dinv, bufA, N);
    k_agg128<<<(N + 7) / 8, 256, 0, stream>>>((const float4*)bufA, row_ptr, sidx, dinv, (float4*)bufB, N);
    k_zero4<<<1, 256, 0, stream>>>((float4*)sums, 64);
    k_bnstats<<<256, 256, 0, stream>>>(bufB, sums, sumsq, N);
    k_bnfinal<<<1, 128, 0, stream>>>(sums, sumsq, g1, be1, scale, shift, N);
    k_bnrelu<<<(n4_128 + 255) / 256, 256, 0, stream>>>((const float4*)bufB, scale, shift, (float4*)bufA, n4_128);

    // ---- layer 2 ----
    k_gemm128<<<(N + 63) / 64, 256, 0, stream>>>(bufA, W2, dinv, bufB, N);
    k_agg128<<<(N + 7) / 8, 256, 0, stream>>>((const float4*)bufB, row_ptr, sidx, dinv, (float4*)bufA, N);
    k_zero4<<<1, 256, 0, stream>>>((float4*)sums, 64);
    k_bnstats<<<256, 256, 0, stream>>>(bufA, sums, sumsq, N);
    k_bnfinal<<<1, 128, 0, stream>>>(sums, sumsq, g2, be2, scale, shift, N);
    k_bnrelu<<<(n4_128 + 255) / 256, 256, 0, stream>>>((const float4*)bufA, scale, shift, (float4*)bufB, n4_128);

    // ---- layer 3 ----
    k_gemm40<<<(int)(((long)N * 40 + 255) / 256), 256, 0, stream>>>(bufB, W3, dinv, t3, N);
    k_agg40<<<(N * 10 + 255) / 256, 256, 0, stream>>>((const float4*)t3, row_ptr, sidx, dinv, b3, (float4*)out, N);
}

// Round 3
// 394.162 us; speedup vs baseline: 8.7936x; 1.2562x over previous
//
#include <hip/hip_runtime.h>
#include <hip/hip_fp16.h>

// ---------------- helpers ----------------

__device__ __forceinline__ void unpack8(uint4 v, float* f) {
    const __half2* hp = (const __half2*)&v;
    float2 a = __half22float2(hp[0]);
    float2 b = __half22float2(hp[1]);
    float2 c = __half22float2(hp[2]);
    float2 d = __half22float2(hp[3]);
    f[0] = a.x; f[1] = a.y; f[2] = b.x; f[3] = b.y;
    f[4] = c.x; f[5] = c.y; f[6] = d.x; f[7] = d.y;
}

__device__ __forceinline__ uint4 pack8(const float* f) {
    __half2 h0 = __floats2half2_rn(f[0], f[1]);
    __half2 h1 = __floats2half2_rn(f[2], f[3]);
    __half2 h2 = __floats2half2_rn(f[4], f[5]);
    __half2 h3 = __floats2half2_rn(f[6], f[7]);
    uint4 v;
    v.x = *(const unsigned int*)&h0;
    v.y = *(const unsigned int*)&h1;
    v.z = *(const unsigned int*)&h2;
    v.w = *(const unsigned int*)&h3;
    return v;
}

__global__ void k_zero4(float4* p, int n4) {
    int i = blockIdx.x * 256 + threadIdx.x;
    if (i < n4) p[i] = make_float4(0.f, 0.f, 0.f, 0.f);
}

// ---------------- CSR build (counting sort by dst) ----------------

__global__ void k_deg(const int* __restrict__ dst, int* __restrict__ deg, int E) {
    int i = blockIdx.x * 256 + threadIdx.x;
    if (i < E) atomicAdd(&deg[dst[i]], 1);
}

__global__ void k_dinv(const int* __restrict__ deg, float* __restrict__ dinv, int n) {
    int i = blockIdx.x * 256 + threadIdx.x;
    if (i < n) {
        int d = deg[i];
        dinv[i] = d > 0 ? rsqrtf((float)d) : 0.f;
    }
}

__global__ void k_blocksum(const int* __restrict__ deg, int* __restrict__ bsum, int n) {
    __shared__ int ls[256];
    int i = blockIdx.x * 256 + threadIdx.x;
    ls[threadIdx.x] = i < n ? deg[i] : 0;
    __syncthreads();
    for (int off = 128; off > 0; off >>= 1) {
        if (threadIdx.x < off) ls[threadIdx.x] += ls[threadIdx.x + off];
        __syncthreads();
    }
    if (threadIdx.x == 0) bsum[blockIdx.x] = ls[0];
}

__global__ void k_scanbsum(int* bsum, int nb) {
    if (threadIdx.x == 0 && blockIdx.x == 0) {
        int acc = 0;
        for (int i = 0; i < nb; ++i) { int v = bsum[i]; bsum[i] = acc; acc += v; }
    }
}

__global__ void k_scanchunk(const int* __restrict__ deg, const int* __restrict__ bsum,
                            int* __restrict__ row_ptr, int* __restrict__ cursor,
                            int n, int E) {
    __shared__ int ls[256];
    int i = blockIdx.x * 256 + threadIdx.x;
    int v = i < n ? deg[i] : 0;
    ls[threadIdx.x] = v;
    __syncthreads();
    for (int off = 1; off < 256; off <<= 1) {
        int t = threadIdx.x >= off ? ls[threadIdx.x - off] : 0;
        __syncthreads();
        ls[threadIdx.x] += t;
        __syncthreads();
    }
    if (i < n) {
        int ex = ls[threadIdx.x] - v + bsum[blockIdx.x];
        row_ptr[i] = ex;
        cursor[i] = ex;
    }
    if (i == n - 1) row_ptr[n] = E;
}

__global__ void k_place(const int* __restrict__ src, const int* __restrict__ dst,
                        int* __restrict__ cursor, int* __restrict__ sidx, int E) {
    int i = blockIdx.x * 256 + threadIdx.x;
    if (i < E) {
        int pos = atomicAdd(&cursor[dst[i]], 1);
        sidx[pos] = src[i];
    }
}

// ---------------- GEMMs (epilogue: x dinv[row], emit fp16) ----------------

// C[row] = fp16(dinv[row] * (A[row] @ W)), A fp32. W (128x128) in LDS.
__global__ __launch_bounds__(256) void k_gemm128_f32A(const float* __restrict__ A,
                                                      const float* __restrict__ W,
                                                      const float* __restrict__ dinv,
                                                      __half* __restrict__ C, int nrows) {
    __shared__ float ws[128 * 128];
    for (int i = threadIdx.x; i < 128 * 128 / 4; i += 256)
        ((float4*)ws)[i] = ((const float4*)W)[i];
    __syncthreads();

    const int col4 = (threadIdx.x & 31) * 4;
    const int rloc = threadIdx.x >> 5;
    const int rowbase = blockIdx.x * 64;
    for (int rp = 0; rp < 8; ++rp) {
        int row = rowbase + rp * 8 + rloc;
        if (row < nrows) {
            const float* a = A + (size_t)row * 128;
            float4 acc = make_float4(0.f, 0.f, 0.f, 0.f);
            for (int kk = 0; kk < 32; ++kk) {
                float4 a4 = ((const float4*)a)[kk];
#pragma unroll
                for (int j = 0; j < 4; ++j) {
                    float av = j == 0 ? a4.x : j == 1 ? a4.y : j == 2 ? a4.z : a4.w;
                    float4 w4 = *(const float4*)&ws[(kk * 4 + j) * 128 + col4];
                    acc.x += av * w4.x; acc.y += av * w4.y;
                    acc.z += av * w4.z; acc.w += av * w4.w;
                }
            }
            float sc = dinv[row];
            __half2 p0 = __floats2half2_rn(acc.x * sc, acc.y * sc);
            __half2 p1 = __floats2half2_rn(acc.z * sc, acc.w * sc);
            uint2 pk;
            pk.x = *(const unsigned int*)&p0;
            pk.y = *(const unsigned int*)&p1;
            *(uint2*)(C + (size_t)row * 128 + col4) = pk;
        }
    }
}

// Same but A is fp16 (post BN+ReLU activations).
__global__ __launch_bounds__(256) void k_gemm128_f16A(const __half* __restrict__ A,
                                                      const float* __restrict__ W,
                                                      const float* __restrict__ dinv,
                                                      __half* __restrict__ C, int nrows) {
    __shared__ float ws[128 * 128];
    for (int i = threadIdx.x; i < 128 * 128 / 4; i += 256)
        ((float4*)ws)[i] = ((const float4*)W)[i];
    __syncthreads();

    const int col4 = (threadIdx.x & 31) * 4;
    const int rloc = threadIdx.x >> 5;
    const int rowbase = blockIdx.x * 64;
    for (int rp = 0; rp < 8; ++rp) {
        int row = rowbase + rp * 8 + rloc;
        if (row < nrows) {
            const uint4* a = (const uint4*)(A + (size_t)row * 128);
            float4 acc = make_float4(0.f, 0.f, 0.f, 0.f);
            for (int kk8 = 0; kk8 < 16; ++kk8) {
                float f[8];
                unpack8(a[kk8], f);
#pragma unroll
                for (int j = 0; j < 8; ++j) {
                    float4 w4 = *(const float4*)&ws[(kk8 * 8 + j) * 128 + col4];
                    acc.x += f[j] * w4.x; acc.y += f[j] * w4.y;
                    acc.z += f[j] * w4.z; acc.w += f[j] * w4.w;
                }
            }
            float sc = dinv[row];
            __half2 p0 = __floats2half2_rn(acc.x * sc, acc.y * sc);
            __half2 p1 = __floats2half2_rn(acc.z * sc, acc.w * sc);
            uint2 pk;
            pk.x = *(const unsigned int*)&p0;
            pk.y = *(const unsigned int*)&p1;
            *(uint2*)(C + (size_t)row * 128 + col4) = pk;
        }
    }
}

// C[N x 40] fp16 = dinv[row] * (A[row] @ W3), A fp16, W3 (128x40) in LDS.
__global__ __launch_bounds__(256) void k_gemm40_f16A(const __half* __restrict__ A,
                                                     const float* __restrict__ W,
                                                     const float* __restrict__ dinv,
                                                     __half* __restrict__ C, int nrows) {
    __shared__ float ws[128 * 40];
    for (int i = threadIdx.x; i < 128 * 40 / 4; i += 256)
        ((float4*)ws)[i] = ((const float4*)W)[i];
    __syncthreads();
    long idx = (long)blockIdx.x * 256 + threadIdx.x;
    long total = (long)nrows * 40;
    if (idx >= total) return;
    int row = (int)(idx / 40);
    int col = (int)(idx % 40);
    const uint4* a = (const uint4*)(A + (size_t)row * 128);
    float acc = 0.f;
    for (int kk8 = 0; kk8 < 16; ++kk8) {
        float f[8];
        unpack8(a[kk8], f);
#pragma unroll
        for (int j = 0; j < 8; ++j)
            acc += f[j] * ws[(kk8 * 8 + j) * 40 + col];
    }
    C[idx] = __float2half(acc * dinv[row]);
}

// ---------------- CSR gather-aggregate (fp16 messages) ----------------

// Hout[d] = fp16(dinv[d] * sum_{j} M[sidx[j]]), F=128.
// 16 lanes per node (8 fp16 cols each via uint4); 16 nodes per block.
__global__ __launch_bounds__(256) void k_agg128_f16(const __half* __restrict__ M,
                                                    const int* __restrict__ rp,
                                                    const int* __restrict__ sidx,
                                                    const float* __restrict__ dinv,
                                                    __half* __restrict__ Hout, int n) {
    int d = blockIdx.x * 16 + (threadIdx.x >> 4);
    if (d >= n) return;
    int lane = threadIdx.x & 15;
    int beg = rp[d], end = rp[d + 1];
    float acc[8] = {0.f, 0.f, 0.f, 0.f, 0.f, 0.f, 0.f, 0.f};
    for (int j = beg; j < end; ++j) {
        int s = sidx[j];
        uint4 v = *(const uint4*)(M + (size_t)s * 128 + lane * 8);
        float f[8];
        unpack8(v, f);
#pragma unroll
        for (int i = 0; i < 8; ++i) acc[i] += f[i];
    }
    float sc = dinv[d];
#pragma unroll
    for (int i = 0; i < 8; ++i) acc[i] *= sc;
    *(uint4*)(Hout + (size_t)d * 128 + lane * 8) = pack8(acc);
}

// out[d] = dinv[d]*sum M3[sidx[j]] + b3, F=40 fp16 in / fp32 out. 5 lanes/node.
__global__ void k_agg40_f16(const __half* __restrict__ M,
                            const int* __restrict__ rp,
                            const int* __restrict__ sidx,
                            const float* __restrict__ dinv,
                            const float* __restrict__ b3,
                            float* __restrict__ out, int n) {
    int i = blockIdx.x * 256 + threadIdx.x;
    if (i >= n * 5) return;
    int d = i / 5, q = i % 5;
    int beg = rp[d], end = rp[d + 1];
    float acc[8] = {0.f, 0.f, 0.f, 0.f, 0.f, 0.f, 0.f, 0.f};
    for (int j = beg; j < end; ++j) {
        int s = sidx[j];
        uint4 v = *(const uint4*)(M + (size_t)s * 40 + q * 8);
        float f[8];
        unpack8(v, f);
#pragma unroll
        for (int k = 0; k < 8; ++k) acc[k] += f[k];
    }
    float sc = dinv[d];
    float4 b0 = *(const float4*)&b3[q * 8];
    float4 b1 = *(const float4*)&b3[q * 8 + 4];
    float4 r0, r1;
    r0.x = acc[0] * sc + b0.x; r0.y = acc[1] * sc + b0.y;
    r0.z = acc[2] * sc + b0.z; r0.w = acc[3] * sc + b0.w;
    r1.x = acc[4] * sc + b1.x; r1.y = acc[5] * sc + b1.y;
    r1.z = acc[6] * sc + b1.z; r1.w = acc[7] * sc + b1.w;
    float* o = out + (size_t)d * 40 + q * 8;
    *(float4*)o = r0;
    *(float4*)(o + 4) = r1;
}

// ---------------- BatchNorm + ReLU (fp16 data) ----------------

__global__ __launch_bounds__(256) void k_bnstats_f16(const __half* __restrict__ H,
                                                     float* __restrict__ sums,
                                                     float* __restrict__ sumsq, int n) {
    int lane = threadIdx.x & 15;   // cols lane*8 .. +8
    int rl = threadIdx.x >> 4;     // 16 rows per block-iter
    float s[8] = {0}, q[8] = {0};
    for (int r = blockIdx.x * 16 + rl; r < n; r += gridDim.x * 16) {
        uint4 v = *(const uint4*)(H + (size_t)r * 128 + lane * 8);
        float f[8];
        unpack8(v, f);
#pragma unroll
        for (int i = 0; i < 8; ++i) { s[i] += f[i]; q[i] += f[i] * f[i]; }
    }
    __shared__ float ls[256][8];
    __shared__ float lq[256][8];
#pragma unroll
    for (int i = 0; i < 8; ++i) { ls[threadIdx.x][i] = s[i]; lq[threadIdx.x][i] = q[i]; }
    __syncthreads();
    if (threadIdx.x < 128) {
        int c = threadIdx.x;
        int lc = c >> 3, e = c & 7;
        float ss = 0.f, qq = 0.f;
        for (int r = 0; r < 16; ++r) {
            ss += ls[r * 16 + lc][e];
            qq += lq[r * 16 + lc][e];
        }
        atomicAdd(&sums[c], ss);
        atomicAdd(&sumsq[c], qq);
    }
}

__global__ void k_bnfinal(const float* __restrict__ sums, const float* __restrict__ sumsq,
                          const float* __restrict__ g, const float* __restrict__ beta,
                          float* __restrict__ scale, float* __restrict__ shift, int nrows) {
    int c = threadIdx.x;
    float inv_n = 1.f / (float)nrows;
    float mu = sums[c] * inv_n;
    float var = sumsq[c] * inv_n - mu * mu;
    float rs = rsqrtf(var + 1e-5f);
    float sc = rs * g[c];
    scale[c] = sc;
    shift[c] = beta[c] - mu * sc;
}

// A[i] = fp16(relu(H[i]*scale + shift)), fp16 in/out, 8 elems/thread.
__global__ void k_bnrelu_f16(const __half* __restrict__ H, const float* __restrict__ scale,
                             const float* __restrict__ shift, __half* __restrict__ A, int n8) {
    int i = blockIdx.x * 256 + threadIdx.x;
    if (i >= n8) return;
    int c8 = (i & 15) * 8;
    uint4 v = ((const uint4*)H)[i];
    float f[8];
    unpack8(v, f);
    float4 s0 = *(const float4*)&scale[c8];
    float4 s1 = *(const float4*)&scale[c8 + 4];
    float4 h0 = *(const float4*)&shift[c8];
    float4 h1 = *(const float4*)&shift[c8 + 4];
    f[0] = fmaxf(f[0] * s0.x + h0.x, 0.f);
    f[1] = fmaxf(f[1] * s0.y + h0.y, 0.f);
    f[2] = fmaxf(f[2] * s0.z + h0.z, 0.f);
    f[3] = fmaxf(f[3] * s0.w + h0.w, 0.f);
    f[4] = fmaxf(f[4] * s1.x + h1.x, 0.f);
    f[5] = fmaxf(f[5] * s1.y + h1.y, 0.f);
    f[6] = fmaxf(f[6] * s1.z + h1.z, 0.f);
    f[7] = fmaxf(f[7] * s1.w + h1.w, 0.f);
    ((uint4*)A)[i] = pack8(f);
}

// ---------------- launch ----------------

extern "C" void kernel_launch(void* const* d_in, const int* in_sizes, int n_in,
                              void* d_out, int out_size, void* d_ws, size_t ws_size,
                              hipStream_t stream) {
    const float* x  = (const float*)d_in[0];
    const int*   ei = (const int*)d_in[1];
    const float* W1 = (const float*)d_in[2];
    const float* g1 = (const float*)d_in[4];
    const float* be1= (const float*)d_in[5];
    const float* W2 = (const float*)d_in[6];
    const float* g2 = (const float*)d_in[8];
    const float* be2= (const float*)d_in[9];
    const float* W3 = (const float*)d_in[10];
    const float* b3 = (const float*)d_in[11];

    const int N = in_sizes[0] / 128;
    const int E = in_sizes[1] / 2;
    const int* srcv = ei;
    const int* dstv = ei + E;
    const int NB = (N + 255) / 256;

    // fp16 buffers first (16B-aligned sizes), then fp32/int
    __half* M    = (__half*)d_ws;                 // N*128
    __half* Hb   = M + (size_t)N * 128;           // N*128
    __half* Ab   = Hb + (size_t)N * 128;          // N*128
    __half* t3   = Ab + (size_t)N * 128;          // N*40
    float* dinv    = (float*)(t3 + (size_t)N * 40);
    int*   deg     = (int*)(dinv + N);
    int*   row_ptr = deg + N;          // N+1
    int*   cursor  = row_ptr + N + 1;  // N
    int*   sidx    = cursor + N;       // E
    int*   bsum    = sidx + E;         // NB
    float* sums    = (float*)(bsum + NB + 1);
    float* sumsq   = sums + 128;
    float* scale   = sumsq + 128;
    float* shift   = scale + 128;
    float* out     = (float*)d_out;

    const int n8_128 = N * 128 / 8;   // uint4 count for N x 128 fp16

    // ---- CSR build + dinv ----
    k_zero4<<<(N / 4 + 255) / 256, 256, 0, stream>>>((float4*)deg, N / 4);
    k_deg<<<(E + 255) / 256, 256, 0, stream>>>(dstv, deg, E);
    k_dinv<<<(N + 255) / 256, 256, 0, stream>>>(deg, dinv, N);
    k_blocksum<<<NB, 256, 0, stream>>>(deg, bsum, N);
    k_scanbsum<<<1, 64, 0, stream>>>(bsum, NB);
    k_scanchunk<<<NB, 256, 0, stream>>>(deg, bsum, row_ptr, cursor, N, E);
    k_place<<<(E + 255) / 256, 256, 0, stream>>>(srcv, dstv, cursor, sidx, E);

    // ---- layer 1 ----
    k_gemm128_f32A<<<(N + 63) / 64, 256, 0, stream>>>(x, W1, dinv, M, N);
    k_agg128_f16<<<(N + 15) / 16, 256, 0, stream>>>(M, row_ptr, sidx, dinv, Hb, N);
    k_zero4<<<1, 256, 0, stream>>>((float4*)sums, 64);
    k_bnstats_f16<<<256, 256, 0, stream>>>(Hb, sums, sumsq, N);
    k_bnfinal<<<1, 128, 0, stream>>>(sums, sumsq, g1, be1, scale, shift, N);
    k_bnrelu_f16<<<(n8_128 + 255) / 256, 256, 0, stream>>>(Hb, scale, shift, Ab, n8_128);

    // ---- layer 2 ----
    k_gemm128_f16A<<<(N + 63) / 64, 256, 0, stream>>>(Ab, W2, dinv, M, N);
    k_agg128_f16<<<(N + 15) / 16, 256, 0, stream>>>(M, row_ptr, sidx, dinv, Hb, N);
    k_zero4<<<1, 256, 0, stream>>>((float4*)sums, 64);
    k_bnstats_f16<<<256, 256, 0, stream>>>(Hb, sums, sumsq, N);
    k_bnfinal<<<1, 128, 0, stream>>>(sums, sumsq, g2, be2, scale, shift, N);
    k_bnrelu_f16<<<(n8_128 + 255) / 256, 256, 0, stream>>>(Hb, scale, shift, Ab, n8_128);

    // ---- layer 3 ----
    k_gemm40_f16A<<<(int)(((long)N * 40 + 255) / 256), 256, 0, stream>>>(Ab, W3, dinv, t3, N);
    k_agg40_f16<<<(N * 5 + 255) / 256, 256, 0, stream>>>(t3, row_ptr, sidx, dinv, b3, out, N);
}

// Round 4
// 309.693 us; speedup vs baseline: 11.1921x; 1.2728x over previous
//
#include <hip/hip_runtime.h>
#include <hip/hip_fp16.h>

typedef _Float16 half8 __attribute__((ext_vector_type(8)));
typedef float floatx4 __attribute__((ext_vector_type(4)));

// ---------------- helpers ----------------

__device__ __forceinline__ void unpack8(uint4 v, float* f) {
    const __half2* hp = (const __half2*)&v;
    float2 a = __half22float2(hp[0]);
    float2 b = __half22float2(hp[1]);
    float2 c = __half22float2(hp[2]);
    float2 d = __half22float2(hp[3]);
    f[0] = a.x; f[1] = a.y; f[2] = b.x; f[3] = b.y;
    f[4] = c.x; f[5] = c.y; f[6] = d.x; f[7] = d.y;
}

__device__ __forceinline__ uint4 pack8(const float* f) {
    __half2 h0 = __floats2half2_rn(f[0], f[1]);
    __half2 h1 = __floats2half2_rn(f[2], f[3]);
    __half2 h2 = __floats2half2_rn(f[4], f[5]);
    __half2 h3 = __floats2half2_rn(f[6], f[7]);
    uint4 v;
    v.x = *(const unsigned int*)&h0;
    v.y = *(const unsigned int*)&h1;
    v.z = *(const unsigned int*)&h2;
    v.w = *(const unsigned int*)&h3;
    return v;
}

__global__ void k_zero4(float4* p, int n4) {
    int i = blockIdx.x * 256 + threadIdx.x;
    if (i < n4) p[i] = make_float4(0.f, 0.f, 0.f, 0.f);
}

// ---------------- CSR build (counting sort by dst) ----------------

__global__ void k_deg(const int* __restrict__ dst, int* __restrict__ deg, int E) {
    int i = blockIdx.x * 256 + threadIdx.x;
    if (i < E) atomicAdd(&deg[dst[i]], 1);
}

__global__ void k_dinv(const int* __restrict__ deg, float* __restrict__ dinv, int n) {
    int i = blockIdx.x * 256 + threadIdx.x;
    if (i < n) {
        int d = deg[i];
        dinv[i] = d > 0 ? rsqrtf((float)d) : 0.f;
    }
}

__global__ void k_blocksum(const int* __restrict__ deg, int* __restrict__ bsum, int n) {
    __shared__ int ls[256];
    int i = blockIdx.x * 256 + threadIdx.x;
    ls[threadIdx.x] = i < n ? deg[i] : 0;
    __syncthreads();
    for (int off = 128; off > 0; off >>= 1) {
        if (threadIdx.x < off) ls[threadIdx.x] += ls[threadIdx.x + off];
        __syncthreads();
    }
    if (threadIdx.x == 0) bsum[blockIdx.x] = ls[0];
}

__global__ void k_scanbsum(int* bsum, int nb) {
    if (threadIdx.x == 0 && blockIdx.x == 0) {
        int acc = 0;
        for (int i = 0; i < nb; ++i) { int v = bsum[i]; bsum[i] = acc; acc += v; }
    }
}

__global__ void k_scanchunk(const int* __restrict__ deg, const int* __restrict__ bsum,
                            int* __restrict__ row_ptr, int* __restrict__ cursor,
                            int n, int E) {
    __shared__ int ls[256];
    int i = blockIdx.x * 256 + threadIdx.x;
    int v = i < n ? deg[i] : 0;
    ls[threadIdx.x] = v;
    __syncthreads();
    for (int off = 1; off < 256; off <<= 1) {
        int t = threadIdx.x >= off ? ls[threadIdx.x - off] : 0;
        __syncthreads();
        ls[threadIdx.x] += t;
        __syncthreads();
    }
    if (i < n) {
        int ex = ls[threadIdx.x] - v + bsum[blockIdx.x];
        row_ptr[i] = ex;
        cursor[i] = ex;
    }
    if (i == n - 1) row_ptr[n] = E;
}

__global__ void k_place(const int* __restrict__ src, const int* __restrict__ dst,
                        int* __restrict__ cursor, int* __restrict__ sidx, int E) {
    int i = blockIdx.x * 256 + threadIdx.x;
    if (i < E) {
        int pos = atomicAdd(&cursor[dst[i]], 1);
        sidx[pos] = src[i];
    }
}

// ---------------- weight pack: W[k][Nw] fp32 -> Wt[Npad][128] fp16 ----------------

__global__ void k_packW(const float* __restrict__ W, __half* __restrict__ Wt,
                        int Nw, int Npad) {
    int i = blockIdx.x * 256 + threadIdx.x;
    if (i >= Npad * 128) return;
    int n = i >> 7, k = i & 127;
    Wt[i] = (n < Nw) ? __float2half(W[(size_t)k * Nw + n]) : __half(0.f);
}

// ---------------- MFMA GEMM ----------------
// C[row][0..OUTW) fp16 = dinv[row] * (A[row] @ W), K=128.
// Wt[n][k] fp16 (transposed W), staged in LDS with XOR swizzle.
// 4 waves/block, 32 rows/wave (2 row-tiles of 16), CT col-tiles of 16.

template <int CT, int OUTW, bool AF32>
__global__ __launch_bounds__(256) void k_gemm_mfma(const void* __restrict__ Ap,
                                                   const __half* __restrict__ Wt,
                                                   const float* __restrict__ dinv,
                                                   __half* __restrict__ C, int nrows) {
    __shared__ char lw[CT * 16 * 256];
    const int nu4 = CT * 16 * 16;  // uint4 count
    for (int i = threadIdx.x; i < nu4; i += 256) {
        int row = i >> 4, k8 = i & 15;
        uint4 v = ((const uint4*)Wt)[i];
        *(uint4*)(lw + ((row * 256 + k8 * 16) ^ ((row & 7) << 4))) = v;
    }
    __syncthreads();

    const int lane = threadIdx.x & 63;
    const int wid = threadIdx.x >> 6;
    const int l15 = lane & 15;
    const int lg = lane >> 4;  // k-group 0..3
    const int rowbase = blockIdx.x * 128 + wid * 32;

    floatx4 acc[2][CT];
#pragma unroll
    for (int r = 0; r < 2; ++r)
#pragma unroll
        for (int c = 0; c < CT; ++c) acc[r][c] = (floatx4){0.f, 0.f, 0.f, 0.f};

    for (int kk = 0; kk < 4; ++kk) {
        half8 afrag[2];
#pragma unroll
        for (int r = 0; r < 2; ++r) {
            int row = rowbase + r * 16 + l15;
            half8 h = {0, 0, 0, 0, 0, 0, 0, 0};
            if (row < nrows) {
                if (AF32) {
                    const float* a = (const float*)Ap + (size_t)row * 128 + kk * 32 + lg * 8;
                    float4 v0 = *(const float4*)a;
                    float4 v1 = *(const float4*)(a + 4);
                    h[0] = (_Float16)v0.x; h[1] = (_Float16)v0.y;
                    h[2] = (_Float16)v0.z; h[3] = (_Float16)v0.w;
                    h[4] = (_Float16)v1.x; h[5] = (_Float16)v1.y;
                    h[6] = (_Float16)v1.z; h[7] = (_Float16)v1.w;
                } else {
                    h = *(const half8*)((const __half*)Ap + (size_t)row * 128 + kk * 32 + lg * 8);
                }
            }
            afrag[r] = h;
        }
#pragma unroll
        for (int c = 0; c < CT; ++c) {
            int wrow = c * 16 + l15;
            half8 bfrag = *(const half8*)(lw + ((wrow * 256 + kk * 64 + lg * 16) ^ ((wrow & 7) << 4)));
#pragma unroll
            for (int r = 0; r < 2; ++r)
                acc[r][c] = __builtin_amdgcn_mfma_f32_16x16x32_f16(afrag[r], bfrag, acc[r][c], 0, 0, 0);
        }
    }

    // epilogue: scale by dinv[row], emit fp16. D: col=lane&15, row=(lane>>4)*4+reg.
#pragma unroll
    for (int r = 0; r < 2; ++r) {
        int rbase = rowbase + r * 16 + lg * 4;
        float d4[4];
#pragma unroll
        for (int j = 0; j < 4; ++j)
            d4[j] = (rbase + j) < nrows ? dinv[rbase + j] : 0.f;
#pragma unroll
        for (int c = 0; c < CT; ++c) {
            int col = c * 16 + l15;
            if (OUTW != CT * 16 && col >= OUTW) continue;
#pragma unroll
            for (int j = 0; j < 4; ++j) {
                int row = rbase + j;
                if (row < nrows)
                    C[(size_t)row * OUTW + col] = __float2half(acc[r][c][j] * d4[j]);
            }
        }
    }
}

// ---------------- CSR gather-aggregate (fp16 messages) ----------------

__global__ __launch_bounds__(256) void k_agg128_f16(const __half* __restrict__ M,
                                                    const int* __restrict__ rp,
                                                    const int* __restrict__ sidx,
                                                    const float* __restrict__ dinv,
                                                    __half* __restrict__ Hout, int n) {
    int d = blockIdx.x * 16 + (threadIdx.x >> 4);
    if (d >= n) return;
    int lane = threadIdx.x & 15;
    int beg = rp[d], end = rp[d + 1];
    float acc[8] = {0.f, 0.f, 0.f, 0.f, 0.f, 0.f, 0.f, 0.f};
    for (int j = beg; j < end; ++j) {
        int s = sidx[j];
        uint4 v = *(const uint4*)(M + (size_t)s * 128 + lane * 8);
        float f[8];
        unpack8(v, f);
#pragma unroll
        for (int i = 0; i < 8; ++i) acc[i] += f[i];
    }
    float sc = dinv[d];
#pragma unroll
    for (int i = 0; i < 8; ++i) acc[i] *= sc;
    *(uint4*)(Hout + (size_t)d * 128 + lane * 8) = pack8(acc);
}

__global__ void k_agg40_f16(const __half* __restrict__ M,
                            const int* __restrict__ rp,
                            const int* __restrict__ sidx,
                            const float* __restrict__ dinv,
                            const float* __restrict__ b3,
                            float* __restrict__ out, int n) {
    int i = blockIdx.x * 256 + threadIdx.x;
    if (i >= n * 5) return;
    int d = i / 5, q = i % 5;
    int beg = rp[d], end = rp[d + 1];
    float acc[8] = {0.f, 0.f, 0.f, 0.f, 0.f, 0.f, 0.f, 0.f};
    for (int j = beg; j < end; ++j) {
        int s = sidx[j];
        uint4 v = *(const uint4*)(M + (size_t)s * 40 + q * 8);
        float f[8];
        unpack8(v, f);
#pragma unroll
        for (int k = 0; k < 8; ++k) acc[k] += f[k];
    }
    float sc = dinv[d];
    float4 b0 = *(const float4*)&b3[q * 8];
    float4 b1 = *(const float4*)&b3[q * 8 + 4];
    float4 r0, r1;
    r0.x = acc[0] * sc + b0.x; r0.y = acc[1] * sc + b0.y;
    r0.z = acc[2] * sc + b0.z; r0.w = acc[3] * sc + b0.w;
    r1.x = acc[4] * sc + b1.x; r1.y = acc[5] * sc + b1.y;
    r1.z = acc[6] * sc + b1.z; r1.w = acc[7] * sc + b1.w;
    float* o = out + (size_t)d * 40 + q * 8;
    *(float4*)o = r0;
    *(float4*)(o + 4) = r1;
}

// ---------------- BatchNorm + ReLU (fp16 data) ----------------

__global__ __launch_bounds__(256) void k_bnstats_f16(const __half* __restrict__ H,
                                                     float* __restrict__ sums,
                                                     float* __restrict__ sumsq, int n) {
    int lane = threadIdx.x & 15;
    int rl = threadIdx.x >> 4;
    float s[8] = {0}, q[8] = {0};
    for (int r = blockIdx.x * 16 + rl; r < n; r += gridDim.x * 16) {
        uint4 v = *(const uint4*)(H + (size_t)r * 128 + lane * 8);
        float f[8];
        unpack8(v, f);
#pragma unroll
        for (int i = 0; i < 8; ++i) { s[i] += f[i]; q[i] += f[i] * f[i]; }
    }
    __shared__ float ls[256][8];
    __shared__ float lq[256][8];
#pragma unroll
    for (int i = 0; i < 8; ++i) { ls[threadIdx.x][i] = s[i]; lq[threadIdx.x][i] = q[i]; }
    __syncthreads();
    if (threadIdx.x < 128) {
        int c = threadIdx.x;
        int lc = c >> 3, e = c & 7;
        float ss = 0.f, qq = 0.f;
        for (int r = 0; r < 16; ++r) {
            ss += ls[r * 16 + lc][e];
            qq += lq[r * 16 + lc][e];
        }
        atomicAdd(&sums[c], ss);
        atomicAdd(&sumsq[c], qq);
    }
}

__global__ void k_bnfinal(const float* __restrict__ sums, const float* __restrict__ sumsq,
                          const float* __restrict__ g, const float* __restrict__ beta,
                          float* __restrict__ scale, float* __restrict__ shift, int nrows) {
    int c = threadIdx.x;
    float inv_n = 1.f / (float)nrows;
    float mu = sums[c] * inv_n;
    float var = sumsq[c] * inv_n - mu * mu;
    float rs = rsqrtf(var + 1e-5f);
    float sc = rs * g[c];
    scale[c] = sc;
    shift[c] = beta[c] - mu * sc;
}

__global__ void k_bnrelu_f16(const __half* __restrict__ H, const float* __restrict__ scale,
                             const float* __restrict__ shift, __half* __restrict__ A, int n8) {
    int i = blockIdx.x * 256 + threadIdx.x;
    if (i >= n8) return;
    int c8 = (i & 15) * 8;
    uint4 v = ((const uint4*)H)[i];
    float f[8];
    unpack8(v, f);
    float4 s0 = *(const float4*)&scale[c8];
    float4 s1 = *(const float4*)&scale[c8 + 4];
    float4 h0 = *(const float4*)&shift[c8];
    float4 h1 = *(const float4*)&shift[c8 + 4];
    f[0] = fmaxf(f[0] * s0.x + h0.x, 0.f);
    f[1] = fmaxf(f[1] * s0.y + h0.y, 0.f);
    f[2] = fmaxf(f[2] * s0.z + h0.z, 0.f);
    f[3] = fmaxf(f[3] * s0.w + h0.w, 0.f);
    f[4] = fmaxf(f[4] * s1.x + h1.x, 0.f);
    f[5] = fmaxf(f[5] * s1.y + h1.y, 0.f);
    f[6] = fmaxf(f[6] * s1.z + h1.z, 0.f);
    f[7] = fmaxf(f[7] * s1.w + h1.w, 0.f);
    ((uint4*)A)[i] = pack8(f);
}

// ---------------- launch ----------------

extern "C" void kernel_launch(void* const* d_in, const int* in_sizes, int n_in,
                              void* d_out, int out_size, void* d_ws, size_t ws_size,
                              hipStream_t stream) {
    const float* x  = (const float*)d_in[0];
    const int*   ei = (const int*)d_in[1];
    const float* W1 = (const float*)d_in[2];
    const float* g1 = (const float*)d_in[4];
    const float* be1= (const float*)d_in[5];
    const float* W2 = (const float*)d_in[6];
    const float* g2 = (const float*)d_in[8];
    const float* be2= (const float*)d_in[9];
    const float* W3 = (const float*)d_in[10];
    const float* b3 = (const float*)d_in[11];

    const int N = in_sizes[0] / 128;
    const int E = in_sizes[1] / 2;
    const int* srcv = ei;
    const int* dstv = ei + E;
    const int NB = (N + 255) / 256;

    __half* M    = (__half*)d_ws;                 // N*128
    __half* Hb   = M + (size_t)N * 128;           // N*128
    __half* Ab   = Hb + (size_t)N * 128;          // N*128
    __half* t3   = Ab + (size_t)N * 128;          // N*40
    float* dinv    = (float*)(t3 + (size_t)N * 40);
    int*   deg     = (int*)(dinv + N);
    int*   row_ptr = deg + N;          // N+1
    int*   cursor  = row_ptr + N + 1;  // N
    int*   sidx    = cursor + N;       // E
    int*   bsum    = sidx + E;         // NB
    float* sums    = (float*)(bsum + NB + 1);
    float* sumsq   = sums + 128;
    float* scale   = sumsq + 128;
    float* shift   = scale + 128;
    __half* Wt1    = (__half*)(shift + 128);      // 128*128
    __half* Wt2    = Wt1 + 128 * 128;             // 128*128
    __half* Wt3    = Wt2 + 128 * 128;             // 48*128
    float* out     = (float*)d_out;

    const int n8_128 = N * 128 / 8;
    const int GB = (N + 127) / 128;  // gemm blocks

    // ---- weight packs + CSR build + dinv ----
    k_packW<<<(128 * 128 + 255) / 256, 256, 0, stream>>>(W1, Wt1, 128, 128);
    k_packW<<<(128 * 128 + 255) / 256, 256, 0, stream>>>(W2, Wt2, 128, 128);
    k_packW<<<(48 * 128 + 255) / 256, 256, 0, stream>>>(W3, Wt3, 40, 48);
    k_zero4<<<(N / 4 + 255) / 256, 256, 0, stream>>>((float4*)deg, N / 4);
    k_deg<<<(E + 255) / 256, 256, 0, stream>>>(dstv, deg, E);
    k_dinv<<<(N + 255) / 256, 256, 0, stream>>>(deg, dinv, N);
    k_blocksum<<<NB, 256, 0, stream>>>(deg, bsum, N);
    k_scanbsum<<<1, 64, 0, stream>>>(bsum, NB);
    k_scanchunk<<<NB, 256, 0, stream>>>(deg, bsum, row_ptr, cursor, N, E);
    k_place<<<(E + 255) / 256, 256, 0, stream>>>(srcv, dstv, cursor, sidx, E);

    // ---- layer 1 ----
    k_gemm_mfma<8, 128, true><<<GB, 256, 0, stream>>>(x, Wt1, dinv, M, N);
    k_agg128_f16<<<(N + 15) / 16, 256, 0, stream>>>(M, row_ptr, sidx, dinv, Hb, N);
    k_zero4<<<1, 256, 0, stream>>>((float4*)sums, 64);
    k_bnstats_f16<<<256, 256, 0, stream>>>(Hb, sums, sumsq, N);
    k_bnfinal<<<1, 128, 0, stream>>>(sums, sumsq, g1, be1, scale, shift, N);
    k_bnrelu_f16<<<(n8_128 + 255) / 256, 256, 0, stream>>>(Hb, scale, shift, Ab, n8_128);

    // ---- layer 2 ----
    k_gemm_mfma<8, 128, false><<<GB, 256, 0, stream>>>(Ab, Wt2, dinv, M, N);
    k_agg128_f16<<<(N + 15) / 16, 256, 0, stream>>>(M, row_ptr, sidx, dinv, Hb, N);
    k_zero4<<<1, 256, 0, stream>>>((float4*)sums, 64);
    k_bnstats_f16<<<256, 256, 0, stream>>>(Hb, sums, sumsq, N);
    k_bnfinal<<<1, 128, 0, stream>>>(sums, sumsq, g2, be2, scale, shift, N);
    k_bnrelu_f16<<<(n8_128 + 255) / 256, 256, 0, stream>>>(Hb, scale, shift, Ab, n8_128);

    // ---- layer 3 ----
    k_gemm_mfma<3, 40, false><<<GB, 256, 0, stream>>>(Ab, Wt3, dinv, t3, N);
    k_agg40_f16<<<(N * 5 + 255) / 256, 256, 0, stream>>>(t3, row_ptr, sidx, dinv, b3, out, N);
}